// Round 1
// baseline (217.626 us; speedup 1.0000x reference)
//
#include <hip/hip_runtime.h>

// Problem constants (from reference setup_inputs)
#define BB 16        // batch
#define TT 288       // time steps
#define NN 4096      // nodes
#define FF 2         // features (only feature 0 used)
#define RR 16        // regions
#define HH 10        // horizon
#define TC 16        // time chunks for phase-1 parallelism (was 8)
#define TSTEP (TT / TC)        // 18
#define NBLK1 (8 * TC * BB)    // k_partial block count = 2048
#define NULLV (-1.0f)

// ---------------------------------------------------------------------------
// Kernel 1: grid (NN/512, TC, BB) = (8,16,16) = 2048 blocks, 256 threads
// (8 blocks/CU, 32 waves/CU -> max wave-level latency hiding).
// Each thread owns 2 consecutive nodes via float4 loads (nodes interleave
// with the 2 features, so one float4 = {n0.f0, n0.f1, n1.f0, n1.f1}).
// Full unroll of the 18-step time loop -> all loads issued before consume.
// Writes per-(tc,b,n) partial sum (f32) / count (u8) and a per-block total
// (bsum/bcnt) for the global imputation mean. Plain stores, no zeroing.
// ---------------------------------------------------------------------------
__global__ __launch_bounds__(256) void k_partial(
    const float4* __restrict__ x4,
    float2* __restrict__ psum2, uchar2* __restrict__ pcnt2,
    float* __restrict__ bsum, unsigned int* __restrict__ bcnt) {
  const int tid = threadIdx.x;
  const int n0  = blockIdx.x * 512 + tid * 2;
  const int tc  = blockIdx.y;
  const int b   = blockIdx.z;

  // float4 index of (b, t=tc*TSTEP, n0, f=0):  ((b*TT+t)*NN + n0)*FF / 4
  const float4* p = x4 + ((size_t)(b * TT + tc * TSTEP) * NN + n0) / 2;
  float s0 = 0.0f, s1 = 0.0f;
  unsigned int c0 = 0, c1 = 0;
#pragma unroll
  for (int t = 0; t < TSTEP; ++t) {
    float4 v = p[(size_t)t * (NN / 2)];
    bool v0 = (v.x != NULLV);
    bool v1 = (v.z != NULLV);
    s0 += v0 ? v.x : 0.0f;  c0 += v0 ? 1u : 0u;
    s1 += v1 ? v.z : 0.0f;  c1 += v1 ? 1u : 0u;
  }
  const size_t o2 = (((size_t)tc * BB + b) * NN + n0) / 2;
  psum2[o2] = make_float2(s0, s1);
  pcnt2[o2] = make_uchar2((unsigned char)c0, (unsigned char)c1);

  // block total -> bsum/bcnt[blockLinear]  (plain store, no atomics)
  float rs = s0 + s1;
  unsigned int rc = c0 + c1;
  for (int off = 32; off > 0; off >>= 1) {
    rs += __shfl_down(rs, off);
    rc += __shfl_down(rc, off);
  }
  __shared__ float sh_s[4];
  __shared__ unsigned int sh_c[4];
  const int wid = tid >> 6;
  if ((tid & 63) == 0) { sh_s[wid] = rs; sh_c[wid] = rc; }
  __syncthreads();
  if (tid == 0) {
    const int blk = (blockIdx.z * TC + blockIdx.y) * 8 + blockIdx.x;
    bsum[blk] = sh_s[0] + sh_s[1] + sh_s[2] + sh_s[3];
    bcnt[blk] = sh_c[0] + sh_c[1] + sh_c[2] + sh_c[3];
  }
}

// ---------------------------------------------------------------------------
// Kernel 2: 64 blocks x 256 threads; each thread owns 4 consecutive nodes.
// (a) every block re-reduces the 2048-entry bsum/bcnt (16 KB, L2-hot) to get
//     the global imputation mean; (b) combines TC partials, imputes, writes
//     the horizon-tiled [B,H,N] prediction with float4 stores; (c) LDS
//     region histogram -> per-block rsB (plain store, no global atomics).
// ---------------------------------------------------------------------------
__global__ __launch_bounds__(256) void k_pred(
    const float4* __restrict__ psum4, const uchar4* __restrict__ pcnt4,
    const float4* __restrict__ bsum4, const uint4* __restrict__ bcnt4,
    const int4* __restrict__ cluster4,
    float4* __restrict__ out4, float* __restrict__ rsB) {
  const int tid = threadIdx.x;
  const int blk = blockIdx.x;          // 64 blocks
  const int b   = blk >> 2;
  const int n0  = (blk & 3) * 1024 + tid * 4;

  // ---- (a) global mean from the 2048 block totals ----
  float4 bsA = bsum4[tid];             // 256 threads x 8 = 2048 entries
  float4 bsB = bsum4[tid + 256];
  uint4  bcA = bcnt4[tid];
  uint4  bcB = bcnt4[tid + 256];
  float rs = bsA.x + bsA.y + bsA.z + bsA.w + bsB.x + bsB.y + bsB.z + bsB.w;
  unsigned int rc = bcA.x + bcA.y + bcA.z + bcA.w +
                    bcB.x + bcB.y + bcB.z + bcB.w;
  for (int off = 32; off > 0; off >>= 1) {
    rs += __shfl_down(rs, off);
    rc += __shfl_down(rc, off);
  }
  __shared__ float sh_s[4];
  __shared__ unsigned int sh_c[4];
  __shared__ float sh_gmean;
  const int wid = tid >> 6;
  if ((tid & 63) == 0) { sh_s[wid] = rs; sh_c[wid] = rc; }
  __syncthreads();
  if (tid == 0) {
    float gs = sh_s[0] + sh_s[1] + sh_s[2] + sh_s[3];
    float gc = (float)(sh_c[0] + sh_c[1] + sh_c[2] + sh_c[3]);
    sh_gmean = gs / fmaxf(gc, 1.0f);
  }
  __syncthreads();
  const float gmean = sh_gmean;

  // ---- (b) combine partials, impute, tile over horizon ----
  float4 s = make_float4(0.f, 0.f, 0.f, 0.f);
  int4 c = make_int4(0, 0, 0, 0);
#pragma unroll
  for (int tc = 0; tc < TC; ++tc) {
    const size_t o4 = (((size_t)tc * BB + b) * NN + n0) / 4;
    float4 ps = psum4[o4];
    uchar4 pc = pcnt4[o4];
    s.x += ps.x; s.y += ps.y; s.z += ps.z; s.w += ps.w;
    c.x += (int)pc.x; c.y += (int)pc.y; c.z += (int)pc.z; c.w += (int)pc.w;
  }
  const float inv_t = 1.0f / (float)TT;
  float4 pred;
  pred.x = (s.x + (float)(TT - c.x) * gmean) * inv_t;
  pred.y = (s.y + (float)(TT - c.y) * gmean) * inv_t;
  pred.z = (s.z + (float)(TT - c.z) * gmean) * inv_t;
  pred.w = (s.w + (float)(TT - c.w) * gmean) * inv_t;

#pragma unroll
  for (int h = 0; h < HH; ++h)
    out4[((size_t)(b * HH + h) * NN + n0) / 4] = pred;

  // ---- (c) per-block regional sums ----
  __shared__ float rsh[RR];
  if (tid < RR) rsh[tid] = 0.0f;
  __syncthreads();
  int4 cl = cluster4[n0 / 4];
  atomicAdd(&rsh[cl.x], pred.x);
  atomicAdd(&rsh[cl.y], pred.y);
  atomicAdd(&rsh[cl.z], pred.z);
  atomicAdd(&rsh[cl.w], pred.w);
  __syncthreads();
  if (tid < RR) rsB[blk * RR + tid] = rsh[tid];
}

// ---------------------------------------------------------------------------
// Kernel 3: single block. Region histogram from cluster_id, combine the 4
// per-quarter block sums per (b,region), divide, write tiled [B,H,R].
// ---------------------------------------------------------------------------
__global__ __launch_bounds__(256) void k_final(
    const int* __restrict__ cluster, const float* __restrict__ rsB,
    float* __restrict__ out2) {
  __shared__ unsigned int hist[RR];
  const int tid = threadIdx.x;
  if (tid < RR) hist[tid] = 0u;
  __syncthreads();
  for (int i = tid; i < NN; i += 256) atomicAdd(&hist[cluster[i]], 1u);
  __syncthreads();
  const int b = tid >> 4;
  const int r = tid & 15;
  float s = 0.0f;
#pragma unroll
  for (int q = 0; q < 4; ++q) s += rsB[((b << 2) + q) * RR + r];
  const float v = s / fmaxf((float)hist[r], 1.0f);
#pragma unroll
  for (int h = 0; h < HH; ++h)
    out2[(size_t)(b * HH + h) * RR + r] = v;
}

extern "C" void kernel_launch(void* const* d_in, const int* in_sizes, int n_in,
                              void* d_out, int out_size, void* d_ws, size_t ws_size,
                              hipStream_t stream) {
  const float* x       = (const float*)d_in[0];  // [B,T,N,F] fp32
  const int*   cluster = (const int*)d_in[1];    // [N] int32
  float* out = (float*)d_out;                    // [B,H,N] then [B,H,R]

  // Workspace layout (every byte written before read each call; no zeroing):
  //   @0        psum  float[TC*BB*NN]   (4 MB)
  //   @4MB      pcnt  u8[TC*BB*NN]      (1 MB)
  //   @5MB      bsum  float[2048]       (8 KB)
  //   @5MB+8K   bcnt  uint[2048]        (8 KB)
  //   @5MB+16K  rsB   float[64*16]      (4 KB)
  float*         psum = (float*)d_ws;
  unsigned char* pcnt = (unsigned char*)d_ws + (size_t)TC * BB * NN * 4;
  float*         bsum = (float*)((char*)d_ws + (size_t)TC * BB * NN * 5);
  unsigned int*  bcnt = (unsigned int*)((char*)bsum + (size_t)NBLK1 * 4);
  float*         rsB  = (float*)((char*)bsum + (size_t)NBLK1 * 8);

  dim3 g1(NN / 512, TC, BB);
  k_partial<<<g1, 256, 0, stream>>>((const float4*)x, (float2*)psum,
                                    (uchar2*)pcnt, bsum, bcnt);

  k_pred<<<64, 256, 0, stream>>>((const float4*)psum, (const uchar4*)pcnt,
                                 (const float4*)bsum, (const uint4*)bcnt,
                                 (const int4*)cluster, (float4*)out, rsB);

  k_final<<<1, 256, 0, stream>>>(cluster, rsB, out + (size_t)BB * HH * NN);
}

// Round 2
// 216.405 us; speedup vs baseline: 1.0056x; 1.0056x over previous
//
#include <hip/hip_runtime.h>

// Problem constants (from reference setup_inputs)
#define BB 16        // batch
#define TT 288       // time steps
#define NN 4096      // nodes
#define FF 2         // features (only feature 0 used)
#define RR 16        // regions
#define HH 10        // horizon
#define TC 16        // time chunks for phase-1 parallelism
#define TSTEP (TT / TC)        // 18
#define NBLK1 (8 * TC * BB)    // k_partial block count = 2048
#define NPRED 256              // k_pred block count
#define NULLV (-1.0f)

// ---------------------------------------------------------------------------
// Kernel 1: grid (NN/512, TC, BB) = (8,16,16) = 2048 blocks, 256 threads.
// __launch_bounds__(256, 8): pin VGPR <= 64 so 8 waves/SIMD stay resident
// (full 18-deep unroll held ~72+ VGPRs of loads in flight -> 4 waves/SIMD).
// unroll 6 keeps ~6 loads in flight/wave: 6*16B*64 lanes*8 waves = 48 KB/SIMD
// in flight vs ~2.3 KB needed for the BW-latency product — ample MLP.
// Each thread owns 2 consecutive nodes via float4 loads (nodes interleave
// with the 2 features: one float4 = {n0.f0, n0.f1, n1.f0, n1.f1}).
// ---------------------------------------------------------------------------
__global__ __launch_bounds__(256, 8) void k_partial(
    const float4* __restrict__ x4,
    float2* __restrict__ psum2, uchar2* __restrict__ pcnt2,
    float* __restrict__ bsum, unsigned int* __restrict__ bcnt) {
  const int tid = threadIdx.x;
  const int n0  = blockIdx.x * 512 + tid * 2;
  const int tc  = blockIdx.y;
  const int b   = blockIdx.z;

  // float4 index of (b, t=tc*TSTEP, n0, f=0):  ((b*TT+t)*NN + n0)*FF / 4
  const float4* p = x4 + ((size_t)(b * TT + tc * TSTEP) * NN + n0) / 2;
  float s0 = 0.0f, s1 = 0.0f;
  unsigned int c0 = 0, c1 = 0;
#pragma unroll 6
  for (int t = 0; t < TSTEP; ++t) {
    float4 v = p[(size_t)t * (NN / 2)];
    bool v0 = (v.x != NULLV);
    bool v1 = (v.z != NULLV);
    s0 += v0 ? v.x : 0.0f;  c0 += v0 ? 1u : 0u;
    s1 += v1 ? v.z : 0.0f;  c1 += v1 ? 1u : 0u;
  }
  const size_t o2 = (((size_t)tc * BB + b) * NN + n0) / 2;
  psum2[o2] = make_float2(s0, s1);
  pcnt2[o2] = make_uchar2((unsigned char)c0, (unsigned char)c1);

  // block total -> bsum/bcnt[blockLinear]  (plain store, no atomics)
  float rs = s0 + s1;
  unsigned int rc = c0 + c1;
  for (int off = 32; off > 0; off >>= 1) {
    rs += __shfl_down(rs, off);
    rc += __shfl_down(rc, off);
  }
  __shared__ float sh_s[4];
  __shared__ unsigned int sh_c[4];
  const int wid = tid >> 6;
  if ((tid & 63) == 0) { sh_s[wid] = rs; sh_c[wid] = rc; }
  __syncthreads();
  if (tid == 0) {
    const int blk = (blockIdx.z * TC + blockIdx.y) * 8 + blockIdx.x;
    bsum[blk] = sh_s[0] + sh_s[1] + sh_s[2] + sh_s[3];
    bcnt[blk] = sh_c[0] + sh_c[1] + sh_c[2] + sh_c[3];
  }
}

// ---------------------------------------------------------------------------
// Kernel 2: 256 blocks x 256 threads (was 64 — engage all CUs for the
// ~8 MB of partial/output traffic). One node per thread, dword-coalesced.
// (a) every block re-reduces the 2048-entry bsum/bcnt (16 KB, L2/L3-hot);
// (b) combines TC partials, imputes, writes horizon-tiled [B,H,N];
// (c) LDS region histogram -> per-block rsB (no global atomics).
// ---------------------------------------------------------------------------
__global__ __launch_bounds__(256) void k_pred(
    const float* __restrict__ psum, const unsigned char* __restrict__ pcnt,
    const float4* __restrict__ bsum4, const uint4* __restrict__ bcnt4,
    const int* __restrict__ cluster,
    float* __restrict__ out, float* __restrict__ rsB) {
  const int tid = threadIdx.x;
  const int blk = blockIdx.x;          // 256 blocks
  const int b   = blk >> 4;
  const int n   = (blk & 15) * 256 + tid;

  // ---- (a) global mean from the 2048 block totals ----
  float4 bsA = bsum4[tid];             // 256 threads x 8 = 2048 entries
  float4 bsB = bsum4[tid + 256];
  uint4  bcA = bcnt4[tid];
  uint4  bcB = bcnt4[tid + 256];
  float rs = bsA.x + bsA.y + bsA.z + bsA.w + bsB.x + bsB.y + bsB.z + bsB.w;
  unsigned int rc = bcA.x + bcA.y + bcA.z + bcA.w +
                    bcB.x + bcB.y + bcB.z + bcB.w;
  for (int off = 32; off > 0; off >>= 1) {
    rs += __shfl_down(rs, off);
    rc += __shfl_down(rc, off);
  }
  __shared__ float sh_s[4];
  __shared__ unsigned int sh_c[4];
  __shared__ float sh_gmean;
  const int wid = tid >> 6;
  if ((tid & 63) == 0) { sh_s[wid] = rs; sh_c[wid] = rc; }
  __syncthreads();
  if (tid == 0) {
    float gs = sh_s[0] + sh_s[1] + sh_s[2] + sh_s[3];
    float gc = (float)(sh_c[0] + sh_c[1] + sh_c[2] + sh_c[3]);
    sh_gmean = gs / fmaxf(gc, 1.0f);
  }
  __syncthreads();
  const float gmean = sh_gmean;

  // ---- (b) combine partials, impute, tile over horizon ----
  float s = 0.0f;
  int   c = 0;
#pragma unroll
  for (int tc = 0; tc < TC; ++tc) {
    const size_t o = ((size_t)tc * BB + b) * NN + n;
    s += psum[o];
    c += (int)pcnt[o];
  }
  const float pred = (s + (float)(TT - c) * gmean) * (1.0f / (float)TT);

#pragma unroll
  for (int h = 0; h < HH; ++h)
    out[(size_t)(b * HH + h) * NN + n] = pred;

  // ---- (c) per-block regional sums ----
  __shared__ float rsh[RR];
  if (tid < RR) rsh[tid] = 0.0f;
  __syncthreads();
  atomicAdd(&rsh[cluster[n]], pred);
  __syncthreads();
  if (tid < RR) rsB[blk * RR + tid] = rsh[tid];
}

// ---------------------------------------------------------------------------
// Kernel 3: single block. Region histogram from cluster_id, combine the 16
// per-part block sums per (b,region), divide, write tiled [B,H,R].
// ---------------------------------------------------------------------------
__global__ __launch_bounds__(256) void k_final(
    const int* __restrict__ cluster, const float* __restrict__ rsB,
    float* __restrict__ out2) {
  __shared__ unsigned int hist[RR];
  const int tid = threadIdx.x;
  if (tid < RR) hist[tid] = 0u;
  __syncthreads();
  for (int i = tid; i < NN; i += 256) atomicAdd(&hist[cluster[i]], 1u);
  __syncthreads();
  const int b = tid >> 4;
  const int r = tid & 15;
  float s = 0.0f;
#pragma unroll
  for (int q = 0; q < 16; ++q) s += rsB[((b << 4) + q) * RR + r];
  const float v = s / fmaxf((float)hist[r], 1.0f);
#pragma unroll
  for (int h = 0; h < HH; ++h)
    out2[(size_t)(b * HH + h) * RR + r] = v;
}

extern "C" void kernel_launch(void* const* d_in, const int* in_sizes, int n_in,
                              void* d_out, int out_size, void* d_ws, size_t ws_size,
                              hipStream_t stream) {
  const float* x       = (const float*)d_in[0];  // [B,T,N,F] fp32
  const int*   cluster = (const int*)d_in[1];    // [N] int32
  float* out = (float*)d_out;                    // [B,H,N] then [B,H,R]

  // Workspace layout (every byte written before read each call; no zeroing):
  //   @0        psum  float[TC*BB*NN]   (4 MB)
  //   @4MB      pcnt  u8[TC*BB*NN]      (1 MB)
  //   @5MB      bsum  float[2048]       (8 KB)
  //   @5MB+8K   bcnt  uint[2048]        (8 KB)
  //   @5MB+16K  rsB   float[256*16]     (16 KB)
  float*         psum = (float*)d_ws;
  unsigned char* pcnt = (unsigned char*)d_ws + (size_t)TC * BB * NN * 4;
  float*         bsum = (float*)((char*)d_ws + (size_t)TC * BB * NN * 5);
  unsigned int*  bcnt = (unsigned int*)((char*)bsum + (size_t)NBLK1 * 4);
  float*         rsB  = (float*)((char*)bsum + (size_t)NBLK1 * 8);

  dim3 g1(NN / 512, TC, BB);
  k_partial<<<g1, 256, 0, stream>>>((const float4*)x, (float2*)psum,
                                    (uchar2*)pcnt, bsum, bcnt);

  k_pred<<<NPRED, 256, 0, stream>>>(psum, pcnt,
                                    (const float4*)bsum, (const uint4*)bcnt,
                                    cluster, out, rsB);

  k_final<<<1, 256, 0, stream>>>(cluster, rsB, out + (size_t)BB * HH * NN);
}